// Round 12
// baseline (255.420 us; speedup 1.0000x reference)
//
#include <hip/hip_runtime.h>

#define V_N    50000
#define E_N    400000
#define NEXT_N 12500
#define B_N    2
#define M_ROWS (V_N * B_N)   // planar GEMM rows: row = b*V_N + v
#define NSBLK  196           // scan blocks: 196*256 = 50176 >= V_N

typedef float  f32x2  __attribute__((ext_vector_type(2)));
typedef float  f32x4  __attribute__((ext_vector_type(4)));
typedef __bf16 bf16x8 __attribute__((ext_vector_type(8)));
typedef int    i32x2  __attribute__((ext_vector_type(2)));
typedef unsigned int u32x2 __attribute__((ext_vector_type(2)));
typedef unsigned int u32x4 __attribute__((ext_vector_type(4)));

__device__ __forceinline__ float bflo(unsigned int u) {
    return __builtin_bit_cast(float, u << 16);
}
__device__ __forceinline__ float bfhi(unsigned int u) {
    return __builtin_bit_cast(float, u & 0xffff0000u);
}
__device__ __forceinline__ unsigned short bf16bits(float f) {
    return __builtin_bit_cast(unsigned short, (__bf16)f);
}

// ---------------- W swizzle helper ----------------
__device__ __forceinline__ void wcvt_one(int idx, int phase,
                                         const float* Wa, const float* Wb, const float* Wc,
                                         unsigned int* dst) {
    int kc = idx >> 11;
    int jj = idx & 3, lane = (idx >> 2) & 63, nt = (idx >> 8) & 7;
    int kk = kc * 32 + ((lane >> 4) * 8) + jj * 2;
    int n  = nt * 16 + (lane & 15);
    const float* Wsrc; int kbase;
    if (phase == 0) {
        if (kk < 64) { Wsrc = Wa; kbase = 0; } else { Wsrc = Wb; kbase = 64; }
    } else {
        if (kk < 128)      { Wsrc = Wa; kbase = 0; }
        else if (kk < 256) { Wsrc = Wb; kbase = 128; }
        else               { Wsrc = Wc; kbase = 256; }
    }
    float w0 = Wsrc[(kk - kbase) * 128 + n];
    float w1 = Wsrc[(kk + 1 - kbase) * 128 + n];
    dst[idx] = ((unsigned int)bf16bits(w1) << 16) | bf16bits(w0);
}

// ---------------- fused prep: xcvt | hist | invmap | wcvt0 | wcvt1 ----------------
// grid = 12500 + 1563 + 196 + 32 + 80 = 14371 blocks
__global__ void prep_kernel(const float* __restrict__ x, unsigned int* __restrict__ xbf,
                            const int* __restrict__ Es, int* __restrict__ degi,
                            const int* __restrict__ poolIdx, const float* __restrict__ poolVal,
                            int* __restrict__ invRow, float* __restrict__ invVal,
                            const float* __restrict__ W0s, const float* __restrict__ W0n,
                            const float* __restrict__ W1s, const float* __restrict__ W1n,
                            const float* __restrict__ Wres,
                            unsigned int* __restrict__ Wc0, unsigned int* __restrict__ Wc1) {
    int blk = blockIdx.x, t = threadIdx.x;
    if (blk < 12500) {                       // xcvt: 3.2M u32 exactly
        int i = blk * 256 + t;
        f32x2 p = *(const f32x2*)(x + (size_t)i * 2);
        xbf[i] = ((unsigned int)bf16bits(p[1]) << 16) | bf16bits(p[0]);
    } else if (blk < 14063) {                // hist
        int e = (blk - 12500) * 256 + t;
        if (e < E_N) atomicAdd(&degi[Es[e]], 1);
    } else if (blk < 14259) {                // invmap (writes EVERY invRow entry)
        int j = (blk - 14063) * 256 + t;
        if (j < V_N) {
            int c = poolIdx[V_N + j];        // fine node
            invRow[c] = poolIdx[j];          // coarse node
            invVal[c] = poolVal[j];
        }
    } else if (blk < 14291) {                // wcvt phase 0 (8192 u32)
        wcvt_one((blk - 14259) * 256 + t, 0, W0s, W0n, nullptr, Wc0);
    } else {                                 // wcvt phase 1 (20480 u32)
        wcvt_one((blk - 14291) * 256 + t, 1, W1s, W1n, Wres, Wc1);
    }
}

// ---------------- single-kernel scan: dynamic rank + published block aggregates ----------
// counter and aggP are zeroed by the memset; aggP stores (blocksum+1), 0 == not ready.
__global__ __launch_bounds__(256) void scan_kernel(const int* __restrict__ degi,
                                                   int* __restrict__ counter,
                                                   int* __restrict__ aggP,
                                                   int* __restrict__ cur,
                                                   float* __restrict__ dinv) {
    __shared__ int sh[256];
    __shared__ int pref[256];
    __shared__ int shrank;
    int t = threadIdx.x;
    if (t == 0) shrank = atomicAdd(counter, 1);
    __syncthreads();
    int rank = shrank;
    int i = rank * 256 + t;
    int d = (i < V_N) ? degi[i] : 0;
    sh[t] = d;
    __syncthreads();
    for (int off = 1; off < 256; off <<= 1) {
        int v = (t >= off) ? sh[t - off] : 0;
        __syncthreads();
        sh[t] += v;
        __syncthreads();
    }
    int incl = sh[t];
    int blocksum = sh[255];
    if (t == 0)
        __hip_atomic_store(&aggP[rank], blocksum + 1, __ATOMIC_RELEASE,
                           __HIP_MEMORY_SCOPE_AGENT);
    // parallel spin: thread t (< rank) waits for block t's aggregate
    int pv = 0;
    if (t < rank) {
        int v;
        do {
            v = __hip_atomic_load(&aggP[t], __ATOMIC_ACQUIRE, __HIP_MEMORY_SCOPE_AGENT);
        } while (v == 0);
        pv = v - 1;
    }
    pref[t] = pv;
    __syncthreads();
    for (int off = 128; off > 0; off >>= 1) {
        if (t < off) pref[t] += pref[t + off];
        __syncthreads();
    }
    int prefix = pref[0];
    if (i < V_N) {
        cur[i] = prefix + incl - d;          // exclusive prefix = row start
        dinv[i] = 1.0f / (float)(d > 1 ? d : 1);
    }
}

// ---------------- CSR fill: combined (dst, val) 8-byte records ----------------
__global__ void csr_kernel(const int* __restrict__ Es, const int* __restrict__ Ee,
                           const float* __restrict__ adj, int* __restrict__ cur,
                           i32x2* __restrict__ ecv) {
    int e = blockIdx.x * 256 + threadIdx.x;
    if (e < E_N) {
        int pos = atomicAdd(&cur[Es[e]], 1);
        i32x2 p;
        p[0] = Ee[e];
        p[1] = __float_as_int(adj[e]);
        ecv[pos] = p;
    }
}
// after csr_kernel: cur[v] == row END of v; row start = cur[v-1] (0 for v=0).

// ---------------- aggregation: one wave per node, 8-edge batched gathers ----------------
// AGG0bf[(b*V+v)*32 + f/2]: dinv[v] * sum_e adj * x[b][dst][f,f+1]
__global__ __launch_bounds__(256) void agg0_kernel(
    const unsigned int* __restrict__ xbf, const int* __restrict__ cur,
    const i32x2* __restrict__ ecv, const float* __restrict__ dinv,
    unsigned int* __restrict__ AGG0bf) {
    int w = blockIdx.x * 4 + (threadIdx.x >> 6);  // node
    int lane = threadIdx.x & 63;
    int beg = w ? cur[w - 1] : 0;
    int end = cur[w];
    int b = lane >> 5, u = lane & 31;
    const unsigned int* src = xbf + (size_t)b * V_N * 32 + u;
    float s0 = 0.f, s1 = 0.f;
    for (int base = beg; base < end; base += 8) {
        int li = base + (lane & 7);
        bool lv = li < end;
        i32x2 ev = lv ? ecv[li] : i32x2{0, 0};
        int dk = ev[0];
        float ak = __int_as_float(ev[1]);
        if (!lv) ak = 0.0f;
        unsigned int pv[8]; float av[8];
#pragma unroll
        for (int j = 0; j < 8; ++j) {
            int dj = __shfl(dk, j);
            av[j] = __shfl(ak, j);
            pv[j] = src[(size_t)dj * 32];
        }
#pragma unroll
        for (int j = 0; j < 8; ++j) { s0 += av[j] * bflo(pv[j]); s1 += av[j] * bfhi(pv[j]); }
    }
    float dv = dinv[w];
    AGG0bf[((size_t)b * V_N + w) * 32 + u] =
        ((unsigned int)bf16bits(s1 * dv) << 16) | bf16bits(s0 * dv);
}

// AGG1bf[(b*V+v)*64 + o/2]: dinv[v] * sum_e adj * OUT0bf[b][dst][o..o+3]
__global__ __launch_bounds__(256) void agg1_kernel(
    const unsigned int* __restrict__ obf, const int* __restrict__ cur,
    const i32x2* __restrict__ ecv, const float* __restrict__ dinv,
    unsigned int* __restrict__ AGG1bf) {
    int w = blockIdx.x * 4 + (threadIdx.x >> 6);
    int lane = threadIdx.x & 63;
    int beg = w ? cur[w - 1] : 0;
    int end = cur[w];
    int b = lane >> 5;
    int u = (lane & 31) * 2;
    const unsigned int* src = obf + (size_t)b * V_N * 64 + u;
    float s[4] = {0, 0, 0, 0};
    for (int base = beg; base < end; base += 8) {
        int li = base + (lane & 7);
        bool lv = li < end;
        i32x2 ev = lv ? ecv[li] : i32x2{0, 0};
        int dk = ev[0];
        float ak = __int_as_float(ev[1]);
        if (!lv) ak = 0.0f;
        u32x2 pv[8]; float av[8];
#pragma unroll
        for (int j = 0; j < 8; ++j) {
            int dj = __shfl(dk, j);
            av[j] = __shfl(ak, j);
            pv[j] = *(const u32x2*)(src + (size_t)dj * 64);
        }
#pragma unroll
        for (int j = 0; j < 8; ++j) {
            s[0] += av[j] * bflo(pv[j][0]); s[1] += av[j] * bfhi(pv[j][0]);
            s[2] += av[j] * bflo(pv[j][1]); s[3] += av[j] * bfhi(pv[j][1]);
        }
    }
    float dv = dinv[w];
    u32x2 r;
    r[0] = ((unsigned int)bf16bits(s[1] * dv) << 16) | bf16bits(s[0] * dv);
    r[1] = ((unsigned int)bf16bits(s[3] * dv) << 16) | bf16bits(s[2] * dv);
    *(u32x2*)(AGG1bf + ((size_t)b * V_N + w) * 64 + u) = r;
}

// ---------------- GEMM: W resident in LDS, barrier-free K-loop, bf16 MFMA ----------------
// PHASE 0: OUT0bf = bf16( leaky( [xbf | AGG0bf] @ W + b0 ) ), K=128
// PHASE 1: pool-store( [OUT0bf | AGG1bf | xbf] @ W + b1 + b_res ), K=320
template <int PHASE>
__global__ __launch_bounds__(256) void gemm_kernel(
    const unsigned int* __restrict__ xbf, const unsigned int* __restrict__ INbf,
    const unsigned int* __restrict__ AGGbf, const unsigned int* __restrict__ Wcvt,
    const float* __restrict__ bias0, const float* __restrict__ bias1,
    const int* __restrict__ invRow, const float* __restrict__ invVal,
    unsigned short* __restrict__ OUTbf, float* __restrict__ out) {
    constexpr int K  = (PHASE == 0) ? 128 : 320;
    constexpr int KC = K / 32;

    __shared__ unsigned int ldsW[KC * 2048];       // 32 KB (P0) / 80 KB (P1)

    const int tid  = threadIdx.x;
    const int wave = tid >> 6, lane = tid & 63;
    const int m = lane & 15, quad = lane >> 4;

    // stage full W once
    {
        const u32x4* src4 = (const u32x4*)Wcvt;
        u32x4* dst4 = (u32x4*)ldsW;
#pragma unroll
        for (int it = 0; it < 2 * KC; ++it) dst4[it * 256 + tid] = src4[it * 256 + tid];
    }
    __syncthreads();

    const int rowA  = blockIdx.x * 64 + wave * 16 + m;       // planar row = b*V + v
    const int rowAc = rowA < M_ROWS ? rowA : M_ROWS - 1;

    f32x4 acc[8];
#pragma unroll
    for (int i = 0; i < 8; ++i)
#pragma unroll
        for (int r = 0; r < 4; ++r) acc[i][r] = 0.0f;

#pragma unroll
    for (int kc = 0; kc < KC; ++kc) {
        int k0 = kc * 32 + quad * 8;
        const unsigned int* abase;
        if (PHASE == 0) {
            abase = (k0 < 64) ? xbf + (size_t)rowAc * 32 + (k0 >> 1)
                              : AGGbf + (size_t)rowAc * 32 + ((k0 - 64) >> 1);
        } else {
            if (k0 < 128)      abase = INbf + (size_t)rowAc * 64 + (k0 >> 1);
            else if (k0 < 256) abase = AGGbf + (size_t)rowAc * 64 + ((k0 - 128) >> 1);
            else               abase = xbf + (size_t)rowAc * 32 + ((k0 - 256) >> 1);
        }
        bf16x8 av = __builtin_bit_cast(bf16x8, *(const u32x4*)abase);
#pragma unroll
        for (int nt = 0; nt < 8; ++nt) {
            bf16x8 bv = __builtin_bit_cast(
                bf16x8, *(const u32x4*)&ldsW[(kc * 8 + nt) * 256 + lane * 4]);
            acc[nt] = __builtin_amdgcn_mfma_f32_16x16x32_bf16(av, bv, acc[nt], 0, 0, 0);
        }
    }

    // ---- epilogue: D[row=(quad*4+r)][col=nt*16+m] ----
    const int rowq = blockIdx.x * 64 + wave * 16 + quad * 4; // first row of this quad
    if (PHASE == 0) {
#pragma unroll
        for (int nt = 0; nt < 8; ++nt) {
            int o = nt * 16 + m;
            float bias = bias0[o];
#pragma unroll
            for (int r = 0; r < 4; ++r) {
                int orow = rowq + r;
                if (orow < M_ROWS) {
                    float val = acc[nt][r] + bias;
                    val = val >= 0.0f ? val : 0.2f * val;
                    OUTbf[(size_t)orow * 128 + o] = bf16bits(val);
                }
            }
        }
    } else {
        // quad's 4 rows = 4 consecutive fine nodes of one batch (rowq divisible by 4;
        // V_N divisible by 4, so no quad spans the batch boundary). For the avg-pool
        // assignment (fine -> fine/4) the 4 rows always map to ONE coarse node, so the
        // uniform store covers every output element exactly once (no d_out memset).
        int b = rowq >= V_N;
        int vq = rowq - b * V_N;
        int rr0 = -2, rr1 = -2, rr2 = -2, rr3 = -2;
        float w0 = 0, w1 = 0, w2 = 0, w3 = 0;
        bool inb = (rowq + 3) < M_ROWS;
        if (inb) {
            rr0 = invRow[vq];     w0 = invVal[vq];
            rr1 = invRow[vq + 1]; w1 = invVal[vq + 1];
            rr2 = invRow[vq + 2]; w2 = invVal[vq + 2];
            rr3 = invRow[vq + 3]; w3 = invVal[vq + 3];
        }
        bool uniform = inb && (rr0 >= 0) && (rr0 == rr1) && (rr0 == rr2) && (rr0 == rr3);
#pragma unroll
        for (int nt = 0; nt < 8; ++nt) {
            int o = nt * 16 + m;
            float bias = bias0[o] + bias1[o];
            if (uniform) {
                float pooled = w0 * (acc[nt][0] + bias) + w1 * (acc[nt][1] + bias) +
                               w2 * (acc[nt][2] + bias) + w3 * (acc[nt][3] + bias);
                out[((size_t)b * NEXT_N + rr0) * 128 + o] = pooled;
            } else {
#pragma unroll
                for (int r = 0; r < 4; ++r) {
                    int orow = rowq + r;
                    if (orow < M_ROWS) {
                        int bb = orow >= V_N;
                        int vf = orow - bb * V_N;
                        int rrr = invRow[vf];
                        float www = invVal[vf];
                        if (rrr >= 0)
                            unsafeAtomicAdd(&out[((size_t)bb * NEXT_N + rrr) * 128 + o],
                                            www * (acc[nt][r] + bias));
                    }
                }
            }
        }
    }
}

// ---------------- launch ----------------

extern "C" void kernel_launch(void* const* d_in, const int* in_sizes, int n_in,
                              void* d_out, int out_size, void* d_ws, size_t ws_size,
                              hipStream_t stream) {
    const float* x       = (const float*)d_in[0];
    const float* adj     = (const float*)d_in[1];
    const int*   Es      = (const int*)d_in[3];
    const int*   Ee      = (const int*)d_in[4];
    const int*   poolIdx = (const int*)d_in[5];
    const float* poolVal = (const float*)d_in[6];
    const float* W_res   = (const float*)d_in[7];
    const float* b_res   = (const float*)d_in[8];
    const float* W0s     = (const float*)d_in[9];
    const float* W0n     = (const float*)d_in[10];
    const float* b0      = (const float*)d_in[11];
    const float* W1s     = (const float*)d_in[12];
    const float* W1n     = (const float*)d_in[13];
    const float* b1      = (const float*)d_in[14];
    float* out = (float*)d_out;

    char* ws = (char*)d_ws;
    int*   invRow  = (int*)  (ws + 0);           // V ints (fully written by invmap)
    float* invVal  = (float*)(ws + 200704);      // V floats
    int*   degi    = (int*)  (ws + 401408);      // V ints -- start of the single memset
    int*   counter = (int*)  (ws + 601408);      // 1 int  -- memset
    int*   aggP    = (int*)  (ws + 601412);      // NSBLK ints -- memset end (200788 B total)
    float* dinv    = (float*)(ws + 602624);      // V floats
    int*   cur     = (int*)  (ws + 803328);      // V ints
    i32x2* ecv     = (i32x2*)(ws + 1003520);     // E x 8 B (dst, val)
    unsigned int* Wc0 = (unsigned int*)(ws + 4203520);   // 8192 u32
    unsigned int* Wc1 = (unsigned int*)(ws + 4236288);   // 20480 u32
    unsigned int* xbf    = (unsigned int*)(ws + 4318208);  // 3.2M u32 (12.8MB)
    unsigned int* AGG0bf = (unsigned int*)(ws + 17118208); // 3.2M u32 (12.8MB)
    unsigned int* OUT0bf = (unsigned int*)(ws + 29918208); // 6.4M u32 (25.6MB)
    unsigned int* AGG1bf = (unsigned int*)(ws + 55518208); // 6.4M u32 (25.6MB) -> ends ~81.1MB

    (void)hipMemsetAsync(degi, 0, 200788, stream);   // degi + counter + aggP

    prep_kernel<<<14371, 256, 0, stream>>>(x, xbf, Es, degi, poolIdx, poolVal,
                                           invRow, invVal, W0s, W0n, W1s, W1n, W_res,
                                           Wc0, Wc1);
    scan_kernel<<<NSBLK, 256, 0, stream>>>(degi, counter, aggP, cur, dinv);
    csr_kernel<<<(E_N + 255) / 256, 256, 0, stream>>>(Es, Ee, adj, cur, ecv);

    agg0_kernel<<<12500, 256, 0, stream>>>(xbf, cur, ecv, dinv, AGG0bf);
    gemm_kernel<0><<<(M_ROWS + 63) / 64, 256, 0, stream>>>(
        xbf, nullptr, AGG0bf, Wc0, b0, nullptr, invRow, invVal,
        (unsigned short*)OUT0bf, nullptr);
    agg1_kernel<<<12500, 256, 0, stream>>>(OUT0bf, cur, ecv, dinv, AGG1bf);
    gemm_kernel<1><<<(M_ROWS + 63) / 64, 256, 0, stream>>>(
        xbf, OUT0bf, AGG1bf, Wc1, b1, b_res, invRow, invVal,
        nullptr, out);
}

// Round 13
// 249.939 us; speedup vs baseline: 1.0219x; 1.0219x over previous
//
#include <hip/hip_runtime.h>

#define V_N    50000
#define E_N    400000
#define NEXT_N 12500
#define B_N    2
#define M_ROWS (V_N * B_N)   // planar GEMM rows: row = b*V_N + v
#define NSBLK  196           // scan blocks: 196*256 = 50176 >= V_N

typedef float  f32x2  __attribute__((ext_vector_type(2)));
typedef float  f32x4  __attribute__((ext_vector_type(4)));
typedef __bf16 bf16x8 __attribute__((ext_vector_type(8)));
typedef int    i32x2  __attribute__((ext_vector_type(2)));
typedef unsigned int u32x2 __attribute__((ext_vector_type(2)));
typedef unsigned int u32x4 __attribute__((ext_vector_type(4)));

__device__ __forceinline__ float bflo(unsigned int u) {
    return __builtin_bit_cast(float, u << 16);
}
__device__ __forceinline__ float bfhi(unsigned int u) {
    return __builtin_bit_cast(float, u & 0xffff0000u);
}
__device__ __forceinline__ unsigned short bf16bits(float f) {
    return __builtin_bit_cast(unsigned short, (__bf16)f);
}

// ---------------- W swizzle helper ----------------
__device__ __forceinline__ void wcvt_one(int idx, int phase,
                                         const float* Wa, const float* Wb, const float* Wc,
                                         unsigned int* dst) {
    int kc = idx >> 11;
    int jj = idx & 3, lane = (idx >> 2) & 63, nt = (idx >> 8) & 7;
    int kk = kc * 32 + ((lane >> 4) * 8) + jj * 2;
    int n  = nt * 16 + (lane & 15);
    const float* Wsrc; int kbase;
    if (phase == 0) {
        if (kk < 64) { Wsrc = Wa; kbase = 0; } else { Wsrc = Wb; kbase = 64; }
    } else {
        if (kk < 128)      { Wsrc = Wa; kbase = 0; }
        else if (kk < 256) { Wsrc = Wb; kbase = 128; }
        else               { Wsrc = Wc; kbase = 256; }
    }
    float w0 = Wsrc[(kk - kbase) * 128 + n];
    float w1 = Wsrc[(kk + 1 - kbase) * 128 + n];
    dst[idx] = ((unsigned int)bf16bits(w1) << 16) | bf16bits(w0);
}

// ---------------- fused prep: xcvt | hist | invmap | wcvt0 | wcvt1 ----------------
// grid = 12500 + 1563 + 196 + 32 + 80 = 14371 blocks
__global__ void prep_kernel(const float* __restrict__ x, unsigned int* __restrict__ xbf,
                            const int* __restrict__ Es, int* __restrict__ degi,
                            const int* __restrict__ poolIdx, const float* __restrict__ poolVal,
                            int* __restrict__ invRow, float* __restrict__ invVal,
                            const float* __restrict__ W0s, const float* __restrict__ W0n,
                            const float* __restrict__ W1s, const float* __restrict__ W1n,
                            const float* __restrict__ Wres,
                            unsigned int* __restrict__ Wc0, unsigned int* __restrict__ Wc1) {
    int blk = blockIdx.x, t = threadIdx.x;
    if (blk < 12500) {                       // xcvt: 3.2M u32 exactly
        int i = blk * 256 + t;
        f32x2 p = *(const f32x2*)(x + (size_t)i * 2);
        xbf[i] = ((unsigned int)bf16bits(p[1]) << 16) | bf16bits(p[0]);
    } else if (blk < 14063) {                // hist
        int e = (blk - 12500) * 256 + t;
        if (e < E_N) atomicAdd(&degi[Es[e]], 1);
    } else if (blk < 14259) {                // invmap (writes EVERY invRow entry)
        int j = (blk - 14063) * 256 + t;
        if (j < V_N) {
            int c = poolIdx[V_N + j];        // fine node
            invRow[c] = poolIdx[j];          // coarse node
            invVal[c] = poolVal[j];
        }
    } else if (blk < 14291) {                // wcvt phase 0 (8192 u32)
        wcvt_one((blk - 14259) * 256 + t, 0, W0s, W0n, nullptr, Wc0);
    } else {                                 // wcvt phase 1 (20480 u32)
        wcvt_one((blk - 14291) * 256 + t, 1, W1s, W1n, Wres, Wc1);
    }
}

// ---------------- single-kernel scan: dynamic rank + published block aggregates ----------
__global__ __launch_bounds__(256) void scan_kernel(const int* __restrict__ degi,
                                                   int* __restrict__ counter,
                                                   int* __restrict__ aggP,
                                                   int* __restrict__ cur,
                                                   float* __restrict__ dinv) {
    __shared__ int sh[256];
    __shared__ int pref[256];
    __shared__ int shrank;
    int t = threadIdx.x;
    if (t == 0) shrank = atomicAdd(counter, 1);
    __syncthreads();
    int rank = shrank;
    int i = rank * 256 + t;
    int d = (i < V_N) ? degi[i] : 0;
    sh[t] = d;
    __syncthreads();
    for (int off = 1; off < 256; off <<= 1) {
        int v = (t >= off) ? sh[t - off] : 0;
        __syncthreads();
        sh[t] += v;
        __syncthreads();
    }
    int incl = sh[t];
    int blocksum = sh[255];
    if (t == 0)
        __hip_atomic_store(&aggP[rank], blocksum + 1, __ATOMIC_RELEASE,
                           __HIP_MEMORY_SCOPE_AGENT);
    int pv = 0;
    if (t < rank) {
        int v;
        do {
            v = __hip_atomic_load(&aggP[t], __ATOMIC_ACQUIRE, __HIP_MEMORY_SCOPE_AGENT);
        } while (v == 0);
        pv = v - 1;
    }
    pref[t] = pv;
    __syncthreads();
    for (int off = 128; off > 0; off >>= 1) {
        if (t < off) pref[t] += pref[t + off];
        __syncthreads();
    }
    int prefix = pref[0];
    if (i < V_N) {
        cur[i] = prefix + incl - d;          // exclusive prefix = row start
        dinv[i] = 1.0f / (float)(d > 1 ? d : 1);
    }
}

// ---------------- CSR fill: 2 edges/thread, combined (dst, val) 8-byte records ----------
__global__ void csr_kernel(const int* __restrict__ Es, const int* __restrict__ Ee,
                           const float* __restrict__ adj, int* __restrict__ cur,
                           i32x2* __restrict__ ecv) {
    int e0 = (blockIdx.x * 256 + threadIdx.x) * 2;
    if (e0 >= E_N) return;
    i32x2 s2 = *(const i32x2*)(Es + e0);
    i32x2 d2 = *(const i32x2*)(Ee + e0);
    f32x2 a2 = *(const f32x2*)(adj + e0);
    {
        int pos = atomicAdd(&cur[s2[0]], 1);
        i32x2 p; p[0] = d2[0]; p[1] = __float_as_int(a2[0]);
        ecv[pos] = p;
    }
    {
        int pos = atomicAdd(&cur[s2[1]], 1);
        i32x2 p; p[0] = d2[1]; p[1] = __float_as_int(a2[1]);
        ecv[pos] = p;
    }
}
// after csr_kernel: cur[v] == row END of v; row start = cur[v-1] (0 for v=0).

// ---------------- aggregation: one wave per node, 32-edge staging, 8-deep gathers --------
// AGG0bf[(b*V+v)*32 + f/2]: dinv[v] * sum_e adj * x[b][dst][f,f+1]
__global__ __launch_bounds__(256) void agg0_kernel(
    const unsigned int* __restrict__ xbf, const int* __restrict__ cur,
    const i32x2* __restrict__ ecv, const float* __restrict__ dinv,
    unsigned int* __restrict__ AGG0bf) {
    int w = blockIdx.x * 4 + (threadIdx.x >> 6);  // node
    int lane = threadIdx.x & 63;
    int beg = w ? cur[w - 1] : 0;
    int end = cur[w];
    int b = lane >> 5, u = lane & 31;
    const unsigned int* src = xbf + (size_t)b * V_N * 32 + u;
    float s0 = 0.f, s1 = 0.f;
    for (int base = beg; base < end; base += 32) {
        int li = base + lane;                 // lanes 0..31 stage one edge each
        bool lv = (lane < 32) && (li < end);
        i32x2 ev = lv ? ecv[li] : i32x2{0, 0};
        int dk = ev[0];
        float ak = lv ? __int_as_float(ev[1]) : 0.0f;
        int nrem = end - base; if (nrem > 32) nrem = 32;
        for (int jb = 0; jb < nrem; jb += 8) {
            unsigned int pv[8]; float av8[8];
#pragma unroll
            for (int j = 0; j < 8; ++j) {
                int dj = __shfl(dk, jb + j);
                av8[j] = __shfl(ak, jb + j);
                pv[j] = src[(size_t)dj * 32];
            }
#pragma unroll
            for (int j = 0; j < 8; ++j) { s0 += av8[j] * bflo(pv[j]); s1 += av8[j] * bfhi(pv[j]); }
        }
    }
    float dv = dinv[w];
    AGG0bf[((size_t)b * V_N + w) * 32 + u] =
        ((unsigned int)bf16bits(s1 * dv) << 16) | bf16bits(s0 * dv);
}

// AGG1bf[(b*V+v)*64 + o/2]: dinv[v] * sum_e adj * OUT0bf[b][dst][o..o+3]
__global__ __launch_bounds__(256) void agg1_kernel(
    const unsigned int* __restrict__ obf, const int* __restrict__ cur,
    const i32x2* __restrict__ ecv, const float* __restrict__ dinv,
    unsigned int* __restrict__ AGG1bf) {
    int w = blockIdx.x * 4 + (threadIdx.x >> 6);
    int lane = threadIdx.x & 63;
    int beg = w ? cur[w - 1] : 0;
    int end = cur[w];
    int b = lane >> 5;
    int u = (lane & 31) * 2;
    const unsigned int* src = obf + (size_t)b * V_N * 64 + u;
    float s[4] = {0, 0, 0, 0};
    for (int base = beg; base < end; base += 32) {
        int li = base + lane;
        bool lv = (lane < 32) && (li < end);
        i32x2 ev = lv ? ecv[li] : i32x2{0, 0};
        int dk = ev[0];
        float ak = lv ? __int_as_float(ev[1]) : 0.0f;
        int nrem = end - base; if (nrem > 32) nrem = 32;
        for (int jb = 0; jb < nrem; jb += 8) {
            u32x2 pv[8]; float av8[8];
#pragma unroll
            for (int j = 0; j < 8; ++j) {
                int dj = __shfl(dk, jb + j);
                av8[j] = __shfl(ak, jb + j);
                pv[j] = *(const u32x2*)(src + (size_t)dj * 64);
            }
#pragma unroll
            for (int j = 0; j < 8; ++j) {
                s[0] += av8[j] * bflo(pv[j][0]); s[1] += av8[j] * bfhi(pv[j][0]);
                s[2] += av8[j] * bflo(pv[j][1]); s[3] += av8[j] * bfhi(pv[j][1]);
            }
        }
    }
    float dv = dinv[w];
    u32x2 r;
    r[0] = ((unsigned int)bf16bits(s[1] * dv) << 16) | bf16bits(s[0] * dv);
    r[1] = ((unsigned int)bf16bits(s[3] * dv) << 16) | bf16bits(s[2] * dv);
    *(u32x2*)(AGG1bf + ((size_t)b * V_N + w) * 64 + u) = r;
}

// ---------------- GEMM: 128 rows/block (2 mtiles/wave), W in LDS once ----------------
// PHASE 0: OUT0bf = bf16( leaky( [xbf | AGG0bf] @ W + b0 ) ), K=128
// PHASE 1: pool-store( [OUT0bf | AGG1bf | xbf] @ W + b1 + b_res ), K=320
template <int PHASE>
__global__ __launch_bounds__(256) void gemm_kernel(
    const unsigned int* __restrict__ xbf, const unsigned int* __restrict__ INbf,
    const unsigned int* __restrict__ AGGbf, const unsigned int* __restrict__ Wcvt,
    const float* __restrict__ bias0, const float* __restrict__ bias1,
    const int* __restrict__ invRow, const float* __restrict__ invVal,
    unsigned short* __restrict__ OUTbf, float* __restrict__ out) {
    constexpr int K  = (PHASE == 0) ? 128 : 320;
    constexpr int KC = K / 32;

    __shared__ unsigned int ldsW[KC * 2048];       // 32 KB (P0) / 80 KB (P1)

    const int tid  = threadIdx.x;
    const int wave = tid >> 6, lane = tid & 63;
    const int m = lane & 15, quad = lane >> 4;

    // stage full W once
    {
        const u32x4* src4 = (const u32x4*)Wcvt;
        u32x4* dst4 = (u32x4*)ldsW;
#pragma unroll
        for (int it = 0; it < 2 * KC; ++it) dst4[it * 256 + tid] = src4[it * 256 + tid];
    }
    __syncthreads();

    const int rowBase = blockIdx.x * 128 + wave * 32;   // 2 mtiles of 16 rows per wave
    int rA[2];
#pragma unroll
    for (int mt = 0; mt < 2; ++mt) {
        int r = rowBase + mt * 16 + m;
        rA[mt] = r < M_ROWS ? r : M_ROWS - 1;
    }

    f32x4 acc[2][8];
#pragma unroll
    for (int mt = 0; mt < 2; ++mt)
#pragma unroll
        for (int i = 0; i < 8; ++i)
#pragma unroll
            for (int r = 0; r < 4; ++r) acc[mt][i][r] = 0.0f;

#pragma unroll
    for (int kc = 0; kc < KC; ++kc) {
        int k0 = kc * 32 + quad * 8;
        bf16x8 av[2];
#pragma unroll
        for (int mt = 0; mt < 2; ++mt) {
            const unsigned int* abase;
            if (PHASE == 0) {
                abase = (k0 < 64) ? xbf + (size_t)rA[mt] * 32 + (k0 >> 1)
                                  : AGGbf + (size_t)rA[mt] * 32 + ((k0 - 64) >> 1);
            } else {
                if (k0 < 128)      abase = INbf + (size_t)rA[mt] * 64 + (k0 >> 1);
                else if (k0 < 256) abase = AGGbf + (size_t)rA[mt] * 64 + ((k0 - 128) >> 1);
                else               abase = xbf + (size_t)rA[mt] * 32 + ((k0 - 256) >> 1);
            }
            av[mt] = __builtin_bit_cast(bf16x8, *(const u32x4*)abase);
        }
#pragma unroll
        for (int nt = 0; nt < 8; ++nt) {
            bf16x8 bv = __builtin_bit_cast(
                bf16x8, *(const u32x4*)&ldsW[(kc * 8 + nt) * 256 + lane * 4]);
            acc[0][nt] = __builtin_amdgcn_mfma_f32_16x16x32_bf16(av[0], bv, acc[0][nt], 0, 0, 0);
            acc[1][nt] = __builtin_amdgcn_mfma_f32_16x16x32_bf16(av[1], bv, acc[1][nt], 0, 0, 0);
        }
    }

    // ---- epilogue per mtile: D[row=(quad*4+r)][col=nt*16+m] ----
#pragma unroll
    for (int mt = 0; mt < 2; ++mt) {
        const int rowq = rowBase + mt * 16 + quad * 4;
        if (PHASE == 0) {
#pragma unroll
            for (int nt = 0; nt < 8; ++nt) {
                int o = nt * 16 + m;
                float bias = bias0[o];
#pragma unroll
                for (int r = 0; r < 4; ++r) {
                    int orow = rowq + r;
                    if (orow < M_ROWS) {
                        float val = acc[mt][nt][r] + bias;
                        val = val >= 0.0f ? val : 0.2f * val;
                        OUTbf[(size_t)orow * 128 + o] = bf16bits(val);
                    }
                }
            }
        } else {
            // quad's 4 rows = 4 consecutive fine nodes of one batch (rowq % 4 == 0,
            // V_N % 4 == 0 so no quad straddles the batch boundary). Avg-pool maps them
            // to ONE coarse node -> uniform store covers every out element exactly once.
            int b = rowq >= V_N;
            int vq = rowq - b * V_N;
            int rr0 = -2, rr1 = -2, rr2 = -2, rr3 = -2;
            float w0 = 0, w1 = 0, w2 = 0, w3 = 0;
            bool inb = (rowq + 3) < M_ROWS;
            if (inb) {
                rr0 = invRow[vq];     w0 = invVal[vq];
                rr1 = invRow[vq + 1]; w1 = invVal[vq + 1];
                rr2 = invRow[vq + 2]; w2 = invVal[vq + 2];
                rr3 = invRow[vq + 3]; w3 = invVal[vq + 3];
            }
            bool uniform = inb && (rr0 >= 0) && (rr0 == rr1) && (rr0 == rr2) && (rr0 == rr3);
#pragma unroll
            for (int nt = 0; nt < 8; ++nt) {
                int o = nt * 16 + m;
                float bias = bias0[o] + bias1[o];
                if (uniform) {
                    float pooled = w0 * (acc[mt][nt][0] + bias) + w1 * (acc[mt][nt][1] + bias) +
                                   w2 * (acc[mt][nt][2] + bias) + w3 * (acc[mt][nt][3] + bias);
                    out[((size_t)b * NEXT_N + rr0) * 128 + o] = pooled;
                } else {
#pragma unroll
                    for (int r = 0; r < 4; ++r) {
                        int orow = rowq + r;
                        if (orow < M_ROWS) {
                            int bb = orow >= V_N;
                            int vf = orow - bb * V_N;
                            int rrr = invRow[vf];
                            float www = invVal[vf];
                            if (rrr >= 0)
                                unsafeAtomicAdd(&out[((size_t)bb * NEXT_N + rrr) * 128 + o],
                                                www * (acc[mt][nt][r] + bias));
                        }
                    }
                }
            }
        }
    }
}

// ---------------- launch ----------------

extern "C" void kernel_launch(void* const* d_in, const int* in_sizes, int n_in,
                              void* d_out, int out_size, void* d_ws, size_t ws_size,
                              hipStream_t stream) {
    const float* x       = (const float*)d_in[0];
    const float* adj     = (const float*)d_in[1];
    const int*   Es      = (const int*)d_in[3];
    const int*   Ee      = (const int*)d_in[4];
    const int*   poolIdx = (const int*)d_in[5];
    const float* poolVal = (const float*)d_in[6];
    const float* W_res   = (const float*)d_in[7];
    const float* b_res   = (const float*)d_in[8];
    const float* W0s     = (const float*)d_in[9];
    const float* W0n     = (const float*)d_in[10];
    const float* b0      = (const float*)d_in[11];
    const float* W1s     = (const float*)d_in[12];
    const float* W1n     = (const float*)d_in[13];
    const float* b1      = (const float*)d_in[14];
    float* out = (float*)d_out;

    char* ws = (char*)d_ws;
    int*   invRow  = (int*)  (ws + 0);           // V ints (fully written by invmap)
    float* invVal  = (float*)(ws + 200704);      // V floats
    int*   degi    = (int*)  (ws + 401408);      // V ints (memset region start)
    int*   counter = (int*)  (ws + 601408);      // 1 int (memset)
    int*   aggP    = (int*)  (ws + 601412);      // NSBLK ints (memset region end, 200788 B)
    float* dinv    = (float*)(ws + 602624);      // V floats
    int*   cur     = (int*)  (ws + 803328);      // V ints
    i32x2* ecv     = (i32x2*)(ws + 1003520);     // E x 8 B (dst, val)
    unsigned int* Wc0 = (unsigned int*)(ws + 4203520);   // 8192 u32
    unsigned int* Wc1 = (unsigned int*)(ws + 4236288);   // 20480 u32
    unsigned int* xbf    = (unsigned int*)(ws + 4318208);  // 3.2M u32 (12.8MB)
    unsigned int* AGG0bf = (unsigned int*)(ws + 17118208); // 3.2M u32 (12.8MB)
    unsigned int* OUT0bf = (unsigned int*)(ws + 29918208); // 6.4M u32 (25.6MB)
    unsigned int* AGG1bf = (unsigned int*)(ws + 55518208); // 6.4M u32 (25.6MB) -> ends ~81.1MB

    (void)hipMemsetAsync(degi, 0, 200788, stream);   // degi + counter + aggP

    prep_kernel<<<14371, 256, 0, stream>>>(x, xbf, Es, degi, poolIdx, poolVal,
                                           invRow, invVal, W0s, W0n, W1s, W1n, W_res,
                                           Wc0, Wc1);
    scan_kernel<<<NSBLK, 256, 0, stream>>>(degi, counter, aggP, cur, dinv);
    csr_kernel<<<(E_N / 2 + 255) / 256, 256, 0, stream>>>(Es, Ee, adj, cur, ecv);

    agg0_kernel<<<12500, 256, 0, stream>>>(xbf, cur, ecv, dinv, AGG0bf);
    gemm_kernel<0><<<(M_ROWS + 127) / 128, 256, 0, stream>>>(
        xbf, nullptr, AGG0bf, Wc0, b0, nullptr, invRow, invVal,
        (unsigned short*)OUT0bf, nullptr);
    agg1_kernel<<<12500, 256, 0, stream>>>(OUT0bf, cur, ecv, dinv, AGG1bf);
    gemm_kernel<1><<<(M_ROWS + 127) / 128, 256, 0, stream>>>(
        xbf, OUT0bf, AGG1bf, Wc1, b1, b_res, invRow, invVal,
        nullptr, out);
}